// Round 6
// baseline (186.283 us; speedup 1.0000x reference)
//
#include <hip/hip_runtime.h>
#include <hip/hip_bf16.h>

#define B_ 4096
#define F_ 8
#define V_ 1000
#define D_ 1024
#define VP 1024

typedef __bf16 bf16x8 __attribute__((ext_vector_type(8)));
typedef float f32x4 __attribute__((ext_vector_type(4)));

__device__ __forceinline__ void gload_lds16(const void* g, void* l) {
  __builtin_amdgcn_global_load_lds(
      (const __attribute__((address_space(1))) void*)g,
      (__attribute__((address_space(3))) void*)l, 16, 0, 0);
}

// ---------------------------------------------------------------------------
// Kernel 0: W (F,D,V) f32 -> Wt (F, VP, D) bf16, zero-padded v in [V,VP)
// ---------------------------------------------------------------------------
__global__ __launch_bounds__(256) void transpose_w(
    const float* __restrict__ W, __hip_bfloat16* __restrict__ Wt) {
  __shared__ float tile[32][33];
  const int f = blockIdx.z;
  const int k0 = blockIdx.x * 32;
  const int v0 = blockIdx.y * 32;
  const int tx = threadIdx.x;
  const int ty = threadIdx.y;
  const float* Wf = W + (size_t)f * D_ * V_;
#pragma unroll
  for (int i = 0; i < 4; ++i) {
    int k = k0 + ty + i * 8;
    int v = v0 + tx;
    tile[ty + i * 8][tx] = (v < V_) ? Wf[k * V_ + v] : 0.0f;
  }
  __syncthreads();
  __hip_bfloat16* Wtf = Wt + (size_t)f * VP * D_;
#pragma unroll
  for (int i = 0; i < 4; ++i) {
    int v = v0 + ty + i * 8;
    int k = k0 + tx;
    Wtf[v * D_ + k] = __float2bfloat16(tile[tx][ty + i * 8]);
  }
}

// ---------------------------------------------------------------------------
// Kernel 1: fused gather + cumsum + LayerNorm + exact gelu -> H (F, B, D) bf16
// ---------------------------------------------------------------------------
__global__ __launch_bounds__(256) void fuse_h(
    const float* __restrict__ emb, const int* __restrict__ feats,
    const float* __restrict__ tables, const float* __restrict__ gamma,
    const float* __restrict__ beta, __hip_bfloat16* __restrict__ H) {
  const int b = blockIdx.x;
  const int t = threadIdx.x;
  const int d = t * 4;
  const int wave = t >> 6, lane = t & 63;

  float s[4];
  {
    float4 v = *reinterpret_cast<const float4*>(&emb[(size_t)b * D_ + d]);
    s[0] = v.x; s[1] = v.y; s[2] = v.z; s[3] = v.w;
  }
  float gm[4], bt[4];
  {
    float4 g = *reinterpret_cast<const float4*>(&gamma[d]);
    float4 bb = *reinterpret_cast<const float4*>(&beta[d]);
    gm[0] = g.x; gm[1] = g.y; gm[2] = g.z; gm[3] = g.w;
    bt[0] = bb.x; bt[1] = bb.y; bt[2] = bb.z; bt[3] = bb.w;
  }
  __shared__ float red[2][4][2];

  for (int f = 0; f < F_; ++f) {
    float sum = s[0] + s[1] + s[2] + s[3];
    float ssq = s[0] * s[0] + s[1] * s[1] + s[2] * s[2] + s[3] * s[3];
#pragma unroll
    for (int off = 32; off > 0; off >>= 1) {
      sum += __shfl_xor(sum, off, 64);
      ssq += __shfl_xor(ssq, off, 64);
    }
    const int pb = f & 1;
    if (lane == 0) { red[pb][wave][0] = sum; red[pb][wave][1] = ssq; }
    __syncthreads();
    sum = red[pb][0][0] + red[pb][1][0] + red[pb][2][0] + red[pb][3][0];
    ssq = red[pb][0][1] + red[pb][1][1] + red[pb][2][1] + red[pb][3][1];

    const float mu = sum * (1.0f / D_);
    const float var = ssq * (1.0f / D_) - mu * mu;
    const float rstd = rsqrtf(var + 1e-5f);

    __hip_bfloat16 hb[4];
#pragma unroll
    for (int j = 0; j < 4; ++j) {
      float x = (s[j] - mu) * rstd * gm[j] + bt[j];
      float g = 0.5f * x * (1.0f + erff(x * 0.70710678118654752f));
      hb[j] = __float2bfloat16(g);
    }
    *reinterpret_cast<uint2*>(&H[(size_t)f * (B_ * D_) + (size_t)b * D_ + d]) =
        *reinterpret_cast<const uint2*>(hb);

    if (f < F_ - 1) {
      int feat = feats[b * F_ + f];
      const float* row = tables + ((size_t)f * V_ + feat) * D_;
      float4 tv = *reinterpret_cast<const float4*>(&row[d]);
      s[0] += tv.x; s[1] += tv.y; s[2] += tv.z; s[3] += tv.w;
    }
  }
}

// ---------------------------------------------------------------------------
// Kernel 2: 256x256 8-phase GEMM, BK=64, 8 waves (2Mx4N), dbuf LDS.
// ALL LDS reads are inline-asm ds_read_b128 (invisible to the compiler's
// waitcnt pass -> no conservative vmcnt(0)/lgkmcnt(0) insertion). Counted
// lgkmcnt per phase, uniform vmcnt(4) at phase end, one raw s_barrier/phase.
// Reads are issued one phase ahead of their MFMA (<=8 b128/phase).
// ---------------------------------------------------------------------------
#define AOFF 0
#define BOFF 32768

#define STAGE(OPB, GB, DBUF, HALF, KT)                                        \
  do {                                                                        \
    const ushort* _g = (GB) + (size_t)(HALF) * (128 * D_) + (size_t)(KT) * 64;\
    ushort* _l = &lds[(OPB) + ((DBUF)*2 + (HALF)) * 8192 + w * 512];          \
    gload_lds16(_g, _l);                                                      \
    gload_lds16(_g + 64 * D_, _l + 4096);                                     \
  } while (0)

#define DSR(D, BASE, O)                                                       \
  asm volatile("ds_read_b128 %0, %1 offset:" O : "=v"(D) : "v"(BASE))

#define RD4(ARR, I0, BASE, O0, O1, O2, O3)                                    \
  do {                                                                        \
    DSR(ARR[(I0) + 0], BASE, O0);                                             \
    DSR(ARR[(I0) + 1], BASE, O1);                                             \
    DSR(ARR[(I0) + 2], BASE, O2);                                             \
    DSR(ARR[(I0) + 3], BASE, O3);                                             \
  } while (0)

#define QMF(AF, BF, R0, C0)                                                   \
  do {                                                                        \
    __builtin_amdgcn_s_setprio(1);                                            \
    _Pragma("unroll") for (int _ks = 0; _ks < 2; ++_ks)                       \
    _Pragma("unroll") for (int _fj = 0; _fj < 4; ++_fj)                       \
    _Pragma("unroll") for (int _fn = 0; _fn < 2; ++_fn)                       \
        acc[(R0) + _fj][(C0) + _fn] =                                         \
            __builtin_amdgcn_mfma_f32_16x16x32_bf16(                          \
                AF[_fj * 2 + _ks], BF[_fn * 2 + _ks],                         \
                acc[(R0) + _fj][(C0) + _fn], 0, 0, 0);                        \
    __builtin_amdgcn_s_setprio(0);                                            \
  } while (0)

#define BAR __builtin_amdgcn_s_barrier()
#define SB0 __builtin_amdgcn_sched_barrier(0)
#define VM4 asm volatile("s_waitcnt vmcnt(4)")
#define LGK(N) asm volatile("s_waitcnt lgkmcnt(" #N ")")

__global__ __launch_bounds__(512, 2) void gemm_hw(
    const ushort* __restrict__ H,    // (F, B, D) bf16
    const ushort* __restrict__ Wt,   // (F, VP, D) bf16
    const float* __restrict__ bias,  // (F, V)
    float* __restrict__ out) {       // (B, F, V)
  __shared__ ushort lds[65536];  // 128 KiB

  // bijective XCD swizzle: nwg=512, 512%8==0
  const int bid = blockIdx.x;
  const int swz = (bid & 7) * 64 + (bid >> 3);
  const int f = swz >> 6;
  const int r = swz & 63;
  const int mt = r >> 2, nt = r & 3;

  const int t = threadIdx.x;
  const int w = t >> 6, l = t & 63;
  const int wm = w >> 2;  // 0..1 (M)
  const int wn = w & 3;   // 0..3 (N)

  const ushort* Hf = H + (size_t)f * (B_ * D_);
  const ushort* Wf = Wt + (size_t)f * (VP * D_);

  // staging global source (pre-swizzled so linear LDS write = swizzled layout)
  const int srow = ((w >> 1) << 4) + (l >> 2);
  const int skx = ((w & 1) << 5) + ((((l & 3) << 3)) ^ (((l >> 5) & 1) << 4));
  const ushort* gA = Hf + (size_t)(mt * 256 + srow) * D_ + skx;
  const ushort* gB = Wf + (size_t)(nt * 256 + srow) * D_ + skx;

  // ds_read per-lane offset (ushorts): same swizzle on read side
  const int laneu =
      ((l & 15) << 5) + (((((l >> 4) << 4)) ^ (((l >> 3) & 1) << 5)) >> 1);
  // byte-address bases for asm ds_read
  const unsigned vA0 = (unsigned)(wm * 8192 + laneu) * 2u;
  const unsigned vA1 = vA0 + 32768u;
  const unsigned vB0 =
      (unsigned)(32768 + (wn >> 1) * 8192 + (wn & 1) * 4096 + laneu) * 2u;
  const unsigned vB1 = vB0 + 32768u;

  bf16x8 a0[8], a1[8], b0f[4], b1f[4];
  f32x4 acc[8][4] = {};

  // prologue: d0{A0,A1,B0,B1}(T0), d1{A0,A1}(T1) = 6 stages (12 vm-ops).
  // vmcnt(4) drains the 4 T0 stages (8 ops) -> d0 certified at BAR.
  STAGE(AOFF, gA, 0, 0, 0);
  STAGE(AOFF, gA, 0, 1, 0);
  STAGE(BOFF, gB, 0, 0, 0);
  STAGE(BOFF, gB, 0, 1, 0);
  STAGE(AOFF, gA, 1, 0, 1);
  STAGE(AOFF, gA, 1, 1, 1);
  VM4;
  BAR;
  // pre-reads for PH1's MFMA: a0(d0,T0), b0(d0,T0)
  RD4(a0, 0, vA0, "0", "1024", "2048", "3072");
  RD4(a0, 4, vA0, "4096", "5120", "6144", "7168");
  RD4(b0f, 0, vB0, "0", "1024", "2048", "3072");
  SB0;

#pragma unroll 1
  for (int i = 0; i < 8; ++i) {
    const int t1 = 2 * i + 1, t2 = 2 * i + 2, t3 = 2 * i + 3;
    const bool more = (i < 7);
    // PH1: read b1(d0,T0); stage d1.B0(T1); MFMA a0xb0 -> acc[0..3][0..1]
    BAR;
    RD4(b1f, 0, vB0, "4096", "5120", "6144", "7168");
    STAGE(BOFF, gB, 1, 0, t1);
    LGK(4);
    SB0;
    QMF(a0, b0f, 0, 0);
    SB0;
    VM4;
    // PH2: read a1(d0,T0); stage d1.B1(T1); MFMA a0xb1 -> acc[0..3][2..3]
    BAR;
    RD4(a1, 0, vA0, "8192", "9216", "10240", "11264");
    RD4(a1, 4, vA0, "12288", "13312", "14336", "15360");
    STAGE(BOFF, gB, 1, 1, t1);
    LGK(8);
    SB0;
    QMF(a0, b1f, 0, 2);
    SB0;
    VM4;
    // PH3: read a0lo(d1,T1); stage d0.A0(T2); MFMA a1xb0 -> acc[4..7][0..1]
    BAR;
    RD4(a0, 0, vA1, "0", "1024", "2048", "3072");
    if (more) STAGE(AOFF, gA, 0, 0, t2);
    LGK(4);
    SB0;
    QMF(a1, b0f, 4, 0);
    SB0;
    VM4;
    // PH4: read a0hi(d1)+b0(d1); stage d0.A1(T2); MFMA a1xb1 -> acc[4..7][2..3]
    BAR;
    RD4(a0, 4, vA1, "4096", "5120", "6144", "7168");
    RD4(b0f, 0, vB1, "0", "1024", "2048", "3072");
    if (more) STAGE(AOFF, gA, 0, 1, t2);
    LGK(12);
    SB0;
    QMF(a1, b1f, 4, 2);
    SB0;
    VM4;
    // PH5: read b1(d1)+a1lo(d1); stage d0.B0(T2); MFMA a0xb0 (d1,T1)
    BAR;
    RD4(b1f, 0, vB1, "4096", "5120", "6144", "7168");
    RD4(a1, 0, vA1, "8192", "9216", "10240", "11264");
    if (more) STAGE(BOFF, gB, 0, 0, t2);
    LGK(8);
    SB0;
    QMF(a0, b0f, 0, 0);
    SB0;
    VM4;
    // PH6: read a1hi(d1); stage d0.B1(T2); MFMA a0xb1 (d1)
    BAR;
    RD4(a1, 4, vA1, "12288", "13312", "14336", "15360");
    if (more) STAGE(BOFF, gB, 0, 1, t2);
    LGK(8);
    SB0;
    QMF(a0, b1f, 0, 2);
    SB0;
    VM4;
    // PH7: read a0(d0,T2); stage d1.A0(T3); MFMA a1xb0 (d1)
    BAR;
    if (more) {
      RD4(a0, 0, vA0, "0", "1024", "2048", "3072");
      RD4(a0, 4, vA0, "4096", "5120", "6144", "7168");
      STAGE(AOFF, gA, 1, 0, t3);
      LGK(8);
    } else {
      LGK(0);
    }
    SB0;
    QMF(a1, b0f, 4, 0);
    SB0;
    VM4;
    // PH8: read b0(d0,T2); stage d1.A1(T3); MFMA a1xb1 (d1)
    BAR;
    if (more) {
      RD4(b0f, 0, vB0, "0", "1024", "2048", "3072");
      STAGE(AOFF, gA, 1, 1, t3);
      LGK(12);
    } else {
      LGK(0);
    }
    SB0;
    QMF(a1, b1f, 4, 2);
    SB0;
    VM4;
  }

  // epilogue: C layout col = lane&15, row = (lane>>4)*4 + q
  const float* bp = bias + f * V_;
  const int orow0 = mt * 256 + wm * 128 + ((l >> 4) << 2);
  const int ocol0 = nt * 256 + wn * 64 + (l & 15);
#pragma unroll
  for (int fi = 0; fi < 8; ++fi) {
#pragma unroll
    for (int fn = 0; fn < 4; ++fn) {
      int col = ocol0 + fn * 16;
      if (col < V_) {
        float bb = bp[col];
        int row = orow0 + fi * 16;
        float* op = out + (size_t)row * (F_ * V_) + (size_t)f * V_ + col;
#pragma unroll
        for (int q = 0; q < 4; ++q)
          op[(size_t)q * (F_ * V_)] = acc[fi][fn][q] + bb;
      }
    }
  }
}

// ---------------------------------------------------------------------------
extern "C" void kernel_launch(void* const* d_in, const int* in_sizes, int n_in,
                              void* d_out, int out_size, void* d_ws,
                              size_t ws_size, hipStream_t stream) {
  const float* emb = (const float*)d_in[0];     // (B, D)
  const int* feats = (const int*)d_in[1];       // (B, F)
  const float* tables = (const float*)d_in[2];  // (F, V, D)
  const float* gamma = (const float*)d_in[3];   // (D,)
  const float* beta = (const float*)d_in[4];    // (D,)
  const float* W = (const float*)d_in[5];       // (F, D, V)
  const float* bias = (const float*)d_in[6];    // (F, V)
  float* out = (float*)d_out;                   // (B, F, V)

  char* ws = (char*)d_ws;
  __hip_bfloat16* Hbuf = (__hip_bfloat16*)ws;  // F*B*D*2 = 64 MiB
  __hip_bfloat16* Wtbuf =
      (__hip_bfloat16*)(ws + (size_t)F_ * B_ * D_ * 2);  // F*VP*D*2 = 16 MiB

  transpose_w<<<dim3(D_ / 32, VP / 32, F_), dim3(32, 8), 0, stream>>>(W, Wtbuf);
  fuse_h<<<dim3(B_), dim3(256), 0, stream>>>(emb, feats, tables, gamma, beta,
                                             Hbuf);
  gemm_hw<<<dim3((B_ / 256) * (VP / 256) * F_), dim3(512), 0, stream>>>(
      (const ushort*)Hbuf, (const ushort*)Wtbuf, bias, out);
}

// Round 7
// 181.956 us; speedup vs baseline: 1.0238x; 1.0238x over previous
//
#include <hip/hip_runtime.h>
#include <hip/hip_bf16.h>

#define B_ 4096
#define F_ 8
#define V_ 1000
#define D_ 1024
#define VP 1024

typedef __bf16 bf16x8 __attribute__((ext_vector_type(8)));
typedef float f32x4 __attribute__((ext_vector_type(4)));

__device__ __forceinline__ void gload_lds16(const void* g, void* l) {
  __builtin_amdgcn_global_load_lds(
      (const __attribute__((address_space(1))) void*)g,
      (__attribute__((address_space(3))) void*)l, 16, 0, 0);
}

// ---------------------------------------------------------------------------
// Kernel 0: W (F,D,V) f32 -> Wt (F, VP, D) bf16, zero-padded v in [V,VP)
// ---------------------------------------------------------------------------
__global__ __launch_bounds__(256) void transpose_w(
    const float* __restrict__ W, __hip_bfloat16* __restrict__ Wt) {
  __shared__ float tile[32][33];
  const int f = blockIdx.z;
  const int k0 = blockIdx.x * 32;
  const int v0 = blockIdx.y * 32;
  const int tx = threadIdx.x;
  const int ty = threadIdx.y;
  const float* Wf = W + (size_t)f * D_ * V_;
#pragma unroll
  for (int i = 0; i < 4; ++i) {
    int k = k0 + ty + i * 8;
    int v = v0 + tx;
    tile[ty + i * 8][tx] = (v < V_) ? Wf[k * V_ + v] : 0.0f;
  }
  __syncthreads();
  __hip_bfloat16* Wtf = Wt + (size_t)f * VP * D_;
#pragma unroll
  for (int i = 0; i < 4; ++i) {
    int v = v0 + ty + i * 8;
    int k = k0 + tx;
    Wtf[v * D_ + k] = __float2bfloat16(tile[tx][ty + i * 8]);
  }
}

// ---------------------------------------------------------------------------
// Kernel 1: fused gather + cumsum + LayerNorm + exact gelu -> H (F, B, D) bf16
// ---------------------------------------------------------------------------
__global__ __launch_bounds__(256) void fuse_h(
    const float* __restrict__ emb, const int* __restrict__ feats,
    const float* __restrict__ tables, const float* __restrict__ gamma,
    const float* __restrict__ beta, __hip_bfloat16* __restrict__ H) {
  const int b = blockIdx.x;
  const int t = threadIdx.x;
  const int d = t * 4;
  const int wave = t >> 6, lane = t & 63;

  float s[4];
  {
    float4 v = *reinterpret_cast<const float4*>(&emb[(size_t)b * D_ + d]);
    s[0] = v.x; s[1] = v.y; s[2] = v.z; s[3] = v.w;
  }
  float gm[4], bt[4];
  {
    float4 g = *reinterpret_cast<const float4*>(&gamma[d]);
    float4 bb = *reinterpret_cast<const float4*>(&beta[d]);
    gm[0] = g.x; gm[1] = g.y; gm[2] = g.z; gm[3] = g.w;
    bt[0] = bb.x; bt[1] = bb.y; bt[2] = bb.z; bt[3] = bb.w;
  }
  __shared__ float red[2][4][2];

  for (int f = 0; f < F_; ++f) {
    float sum = s[0] + s[1] + s[2] + s[3];
    float ssq = s[0] * s[0] + s[1] * s[1] + s[2] * s[2] + s[3] * s[3];
#pragma unroll
    for (int off = 32; off > 0; off >>= 1) {
      sum += __shfl_xor(sum, off, 64);
      ssq += __shfl_xor(ssq, off, 64);
    }
    const int pb = f & 1;
    if (lane == 0) { red[pb][wave][0] = sum; red[pb][wave][1] = ssq; }
    __syncthreads();
    sum = red[pb][0][0] + red[pb][1][0] + red[pb][2][0] + red[pb][3][0];
    ssq = red[pb][0][1] + red[pb][1][1] + red[pb][2][1] + red[pb][3][1];

    const float mu = sum * (1.0f / D_);
    const float var = ssq * (1.0f / D_) - mu * mu;
    const float rstd = rsqrtf(var + 1e-5f);

    __hip_bfloat16 hb[4];
#pragma unroll
    for (int j = 0; j < 4; ++j) {
      float x = (s[j] - mu) * rstd * gm[j] + bt[j];
      float g = 0.5f * x * (1.0f + erff(x * 0.70710678118654752f));
      hb[j] = __float2bfloat16(g);
    }
    *reinterpret_cast<uint2*>(&H[(size_t)f * (B_ * D_) + (size_t)b * D_ + d]) =
        *reinterpret_cast<const uint2*>(hb);

    if (f < F_ - 1) {
      int feat = feats[b * F_ + f];
      const float* row = tables + ((size_t)f * V_ + feat) * D_;
      float4 tv = *reinterpret_cast<const float4*>(&row[d]);
      s[0] += tv.x; s[1] += tv.y; s[2] += tv.z; s[3] += tv.w;
    }
  }
}

// ---------------------------------------------------------------------------
// Kernel 2: 256x256 GEMM, BK=64, 8 waves (2Mx4N), dbuf LDS, asm ds_read
// (invisible to the compiler's alias-conservative waitcnt pass).
// Quadrant rotation per K-tile: (aL,bL)(aL,bH)(aH,bH)(aH,bL) -- each phase
// prefetches ONLY the operand that changes next => peak frag liveness 96 VGPR.
// Stages: all 4 half-tiles of T+1 at Q1(T); vmcnt(4)@Q2-end certifies A(T+1),
// vmcnt(0)@Q3-end certifies B(T+1) (only >=2-phase-old loads ever waited on).
// ---------------------------------------------------------------------------
#define AOFF 0
#define BOFF 32768

#define STAGE(OPB, GB, DBUF, HALF, KT)                                        \
  do {                                                                        \
    const ushort* _g = (GB) + (size_t)(HALF) * (128 * D_) + (size_t)(KT) * 64;\
    ushort* _l = &lds[(OPB) + ((DBUF)*2 + (HALF)) * 8192 + w * 512];          \
    gload_lds16(_g, _l);                                                      \
    gload_lds16(_g + 64 * D_, _l + 4096);                                     \
  } while (0)

#define DSR(D, BASE, O)                                                       \
  asm volatile("ds_read_b128 %0, %1 offset:" O : "=v"(D) : "v"(BASE))

#define RD4(ARR, I0, BASE, O0, O1, O2, O3)                                    \
  do {                                                                        \
    DSR(ARR[(I0) + 0], BASE, O0);                                             \
    DSR(ARR[(I0) + 1], BASE, O1);                                             \
    DSR(ARR[(I0) + 2], BASE, O2);                                             \
    DSR(ARR[(I0) + 3], BASE, O3);                                             \
  } while (0)

#define QMF(AF, BF, R0, C0)                                                   \
  do {                                                                        \
    __builtin_amdgcn_s_setprio(1);                                            \
    _Pragma("unroll") for (int _ks = 0; _ks < 2; ++_ks)                       \
    _Pragma("unroll") for (int _fj = 0; _fj < 4; ++_fj)                       \
    _Pragma("unroll") for (int _fn = 0; _fn < 2; ++_fn)                       \
        acc[(R0) + _fj][(C0) + _fn] =                                         \
            __builtin_amdgcn_mfma_f32_16x16x32_bf16(                          \
                AF[_fj * 2 + _ks], BF[_fn * 2 + _ks],                         \
                acc[(R0) + _fj][(C0) + _fn], 0, 0, 0);                        \
    __builtin_amdgcn_s_setprio(0);                                            \
  } while (0)

#define BAR __builtin_amdgcn_s_barrier()
#define SB0 __builtin_amdgcn_sched_barrier(0)
#define VM4 asm volatile("s_waitcnt vmcnt(4)")
#define VM0 asm volatile("s_waitcnt vmcnt(0)")
#define LGK(N) asm volatile("s_waitcnt lgkmcnt(" #N ")")

__global__ __launch_bounds__(512, 2) void gemm_hw(
    const ushort* __restrict__ H,    // (F, B, D) bf16
    const ushort* __restrict__ Wt,   // (F, VP, D) bf16
    const float* __restrict__ bias,  // (F, V)
    float* __restrict__ out) {       // (B, F, V)
  __shared__ ushort lds[65536];  // 128 KiB

  // bijective XCD swizzle: nwg=512, 512%8==0
  const int bid = blockIdx.x;
  const int swz = (bid & 7) * 64 + (bid >> 3);
  const int f = swz >> 6;
  const int r = swz & 63;
  const int mt = r >> 2, nt = r & 3;

  const int t = threadIdx.x;
  const int w = t >> 6, l = t & 63;
  const int wm = w >> 2;  // 0..1 (M)
  const int wn = w & 3;   // 0..3 (N)

  const ushort* Hf = H + (size_t)f * (B_ * D_);
  const ushort* Wf = Wt + (size_t)f * (VP * D_);

  // staging global source (pre-swizzled so linear LDS write = swizzled layout)
  const int srow = ((w >> 1) << 4) + (l >> 2);
  const int skx = ((w & 1) << 5) + ((((l & 3) << 3)) ^ (((l >> 5) & 1) << 4));
  const ushort* gA = Hf + (size_t)(mt * 256 + srow) * D_ + skx;
  const ushort* gB = Wf + (size_t)(nt * 256 + srow) * D_ + skx;

  // ds_read per-lane offset (ushorts): same swizzle on read side
  const int laneu =
      ((l & 15) << 5) + (((((l >> 4) << 4)) ^ (((l >> 3) & 1) << 5)) >> 1);
  // byte-address bases for asm ds_read
  const unsigned vA0 = (unsigned)(wm * 8192 + laneu) * 2u;   // dbuf0, own half
  const unsigned vA1 = vA0 + 32768u;                         // dbuf1
  const unsigned vB0 =
      (unsigned)(32768 + (wn >> 1) * 8192 + (wn & 1) * 4096 + laneu) * 2u;
  const unsigned vB1 = vB0 + 32768u;

  // fragment slots: a0 = aL (fj0-3), a1 = aH (fj4-7); bx/by alternate roles
  bf16x8 a0[8], a1[8], bx[4], by[4];
  f32x4 acc[8][4] = {};

  // prologue: stage tile0 (A both halves, B both halves) into dbuf0
  STAGE(AOFF, gA, 0, 0, 0);
  STAGE(AOFF, gA, 0, 1, 0);
  STAGE(BOFF, gB, 0, 0, 0);
  STAGE(BOFF, gB, 0, 1, 0);
  VM0;
  BAR;
  // pre-reads for P1: aL(T0), bL(T0)->bx
  RD4(a0, 0, vA0, "0", "1024", "2048", "3072");
  RD4(a0, 4, vA0, "4096", "5120", "6144", "7168");
  RD4(bx, 0, vB0, "0", "1024", "2048", "3072");
  SB0;

#pragma unroll 1
  for (int i = 0; i < 8; ++i) {
    const int tO = 2 * i + 1;   // odd tile -> dbuf1
    const int tE2 = 2 * i + 2;  // next even tile -> dbuf0
    const bool more = (i < 7);
    // P1 (E.Q1): rd bH(E)->by; stage all of tile O; MFMA aL*bL
    BAR;
    RD4(by, 0, vB0, "4096", "5120", "6144", "7168");
    STAGE(AOFF, gA, 1, 0, tO);
    STAGE(AOFF, gA, 1, 1, tO);
    STAGE(BOFF, gB, 1, 0, tO);
    STAGE(BOFF, gB, 1, 1, tO);
    LGK(4);
    SB0;
    QMF(a0, bx, 0, 0);
    SB0;
    // P2 (E.Q2): rd aH(E)->a1; MFMA aL*bH; certify A(O)
    BAR;
    RD4(a1, 0, vA0, "8192", "9216", "10240", "11264");
    RD4(a1, 4, vA0, "12288", "13312", "14336", "15360");
    LGK(8);
    SB0;
    QMF(a0, by, 0, 2);
    SB0;
    VM4;
    // P3 (E.Q3): rd aL(O)->a0; MFMA aH*bH; certify B(O)
    BAR;
    RD4(a0, 0, vA1, "0", "1024", "2048", "3072");
    RD4(a0, 4, vA1, "4096", "5120", "6144", "7168");
    LGK(8);
    SB0;
    QMF(a1, by, 4, 2);
    SB0;
    VM0;
    // P4 (E.Q4): rd bL(O)->by; MFMA aH*bL
    BAR;
    RD4(by, 0, vB1, "0", "1024", "2048", "3072");
    LGK(12);
    SB0;
    QMF(a1, bx, 4, 0);
    SB0;
    // P5 (O.Q1): rd bH(O)->bx; stage all of tile E'; MFMA aL*bL (=a0*by)
    BAR;
    RD4(bx, 0, vB1, "4096", "5120", "6144", "7168");
    if (more) {
      STAGE(AOFF, gA, 0, 0, tE2);
      STAGE(AOFF, gA, 0, 1, tE2);
      STAGE(BOFF, gB, 0, 0, tE2);
      STAGE(BOFF, gB, 0, 1, tE2);
    }
    LGK(4);
    SB0;
    QMF(a0, by, 0, 0);
    SB0;
    // P6 (O.Q2): rd aH(O)->a1; MFMA aL*bH (=a0*bx); certify A(E')
    BAR;
    RD4(a1, 0, vA1, "8192", "9216", "10240", "11264");
    RD4(a1, 4, vA1, "12288", "13312", "14336", "15360");
    LGK(8);
    SB0;
    QMF(a0, bx, 0, 2);
    SB0;
    VM4;
    // P7 (O.Q3): rd aL(E')->a0; MFMA aH*bH (=a1*bx); certify B(E')
    BAR;
    if (more) {
      RD4(a0, 0, vA0, "0", "1024", "2048", "3072");
      RD4(a0, 4, vA0, "4096", "5120", "6144", "7168");
      LGK(8);
    } else {
      LGK(0);
    }
    SB0;
    QMF(a1, bx, 4, 2);
    SB0;
    VM0;
    // P8 (O.Q4): rd bL(E')->bx; MFMA aH*bL (=a1*by)
    BAR;
    if (more) {
      RD4(bx, 0, vB0, "0", "1024", "2048", "3072");
      LGK(12);
    } else {
      LGK(0);
    }
    SB0;
    QMF(a1, by, 4, 0);
    SB0;
  }

  // epilogue: C layout col = lane&15, row = (lane>>4)*4 + q
  const float* bp = bias + f * V_;
  const int orow0 = mt * 256 + wm * 128 + ((l >> 4) << 2);
  const int ocol0 = nt * 256 + wn * 64 + (l & 15);
#pragma unroll
  for (int fi = 0; fi < 8; ++fi) {
#pragma unroll
    for (int fn = 0; fn < 4; ++fn) {
      int col = ocol0 + fn * 16;
      if (col < V_) {
        float bb = bp[col];
        int row = orow0 + fi * 16;
        float* op = out + (size_t)row * (F_ * V_) + (size_t)f * V_ + col;
#pragma unroll
        for (int q = 0; q < 4; ++q)
          op[(size_t)q * (F_ * V_)] = acc[fi][fn][q] + bb;
      }
    }
  }
}

// ---------------------------------------------------------------------------
extern "C" void kernel_launch(void* const* d_in, const int* in_sizes, int n_in,
                              void* d_out, int out_size, void* d_ws,
                              size_t ws_size, hipStream_t stream) {
  const float* emb = (const float*)d_in[0];     // (B, D)
  const int* feats = (const int*)d_in[1];       // (B, F)
  const float* tables = (const float*)d_in[2];  // (F, V, D)
  const float* gamma = (const float*)d_in[3];   // (D,)
  const float* beta = (const float*)d_in[4];    // (D,)
  const float* W = (const float*)d_in[5];       // (F, D, V)
  const float* bias = (const float*)d_in[6];    // (F, V)
  float* out = (float*)d_out;                   // (B, F, V)

  char* ws = (char*)d_ws;
  __hip_bfloat16* Hbuf = (__hip_bfloat16*)ws;  // F*B*D*2 = 64 MiB
  __hip_bfloat16* Wtbuf =
      (__hip_bfloat16*)(ws + (size_t)F_ * B_ * D_ * 2);  // F*VP*D*2 = 16 MiB

  transpose_w<<<dim3(D_ / 32, VP / 32, F_), dim3(32, 8), 0, stream>>>(W, Wtbuf);
  fuse_h<<<dim3(B_), dim3(256), 0, stream>>>(emb, feats, tables, gamma, beta,
                                             Hbuf);
  gemm_hw<<<dim3((B_ / 256) * (VP / 256) * F_), dim3(512), 0, stream>>>(
      (const ushort*)Hbuf, (const ushort*)Wtbuf, bias, out);
}

// Round 9
// 137.241 us; speedup vs baseline: 1.3573x; 1.3258x over previous
//
#include <hip/hip_runtime.h>
#include <hip/hip_bf16.h>

#define B_ 4096
#define F_ 8
#define V_ 1000
#define D_ 1024
#define VP 1024

typedef __bf16 bf16x8 __attribute__((ext_vector_type(8)));
typedef float f32x4 __attribute__((ext_vector_type(4)));

__device__ __forceinline__ void gload_lds16(const void* g, void* l) {
  __builtin_amdgcn_global_load_lds(
      (const __attribute__((address_space(1))) void*)g,
      (__attribute__((address_space(3))) void*)l, 16, 0, 0);
}

// ---------------------------------------------------------------------------
// Kernel 0: W (F,D,V) f32 -> Wt (F, VP, D) bf16, zero-padded v in [V,VP)
// ---------------------------------------------------------------------------
__global__ __launch_bounds__(256) void transpose_w(
    const float* __restrict__ W, __hip_bfloat16* __restrict__ Wt) {
  __shared__ float tile[32][33];
  const int f = blockIdx.z;
  const int k0 = blockIdx.x * 32;
  const int v0 = blockIdx.y * 32;
  const int tx = threadIdx.x;
  const int ty = threadIdx.y;
  const float* Wf = W + (size_t)f * D_ * V_;
#pragma unroll
  for (int i = 0; i < 4; ++i) {
    int k = k0 + ty + i * 8;
    int v = v0 + tx;
    tile[ty + i * 8][tx] = (v < V_) ? Wf[k * V_ + v] : 0.0f;
  }
  __syncthreads();
  __hip_bfloat16* Wtf = Wt + (size_t)f * VP * D_;
#pragma unroll
  for (int i = 0; i < 4; ++i) {
    int v = v0 + ty + i * 8;
    int k = k0 + tx;
    Wtf[v * D_ + k] = __float2bfloat16(tile[tx][ty + i * 8]);
  }
}

// ---------------------------------------------------------------------------
// Kernel 1: fused gather + cumsum + LayerNorm + exact gelu -> H (F, B, D) bf16
// ---------------------------------------------------------------------------
__global__ __launch_bounds__(256) void fuse_h(
    const float* __restrict__ emb, const int* __restrict__ feats,
    const float* __restrict__ tables, const float* __restrict__ gamma,
    const float* __restrict__ beta, __hip_bfloat16* __restrict__ H) {
  const int b = blockIdx.x;
  const int t = threadIdx.x;
  const int d = t * 4;
  const int wave = t >> 6, lane = t & 63;

  float s[4];
  {
    float4 v = *reinterpret_cast<const float4*>(&emb[(size_t)b * D_ + d]);
    s[0] = v.x; s[1] = v.y; s[2] = v.z; s[3] = v.w;
  }
  float gm[4], bt[4];
  {
    float4 g = *reinterpret_cast<const float4*>(&gamma[d]);
    float4 bb = *reinterpret_cast<const float4*>(&beta[d]);
    gm[0] = g.x; gm[1] = g.y; gm[2] = g.z; gm[3] = g.w;
    bt[0] = bb.x; bt[1] = bb.y; bt[2] = bb.z; bt[3] = bb.w;
  }
  __shared__ float red[2][4][2];

  for (int f = 0; f < F_; ++f) {
    float sum = s[0] + s[1] + s[2] + s[3];
    float ssq = s[0] * s[0] + s[1] * s[1] + s[2] * s[2] + s[3] * s[3];
#pragma unroll
    for (int off = 32; off > 0; off >>= 1) {
      sum += __shfl_xor(sum, off, 64);
      ssq += __shfl_xor(ssq, off, 64);
    }
    const int pb = f & 1;
    if (lane == 0) { red[pb][wave][0] = sum; red[pb][wave][1] = ssq; }
    __syncthreads();
    sum = red[pb][0][0] + red[pb][1][0] + red[pb][2][0] + red[pb][3][0];
    ssq = red[pb][0][1] + red[pb][1][1] + red[pb][2][1] + red[pb][3][1];

    const float mu = sum * (1.0f / D_);
    const float var = ssq * (1.0f / D_) - mu * mu;
    const float rstd = rsqrtf(var + 1e-5f);

    __hip_bfloat16 hb[4];
#pragma unroll
    for (int j = 0; j < 4; ++j) {
      float x = (s[j] - mu) * rstd * gm[j] + bt[j];
      float g = 0.5f * x * (1.0f + erff(x * 0.70710678118654752f));
      hb[j] = __float2bfloat16(g);
    }
    *reinterpret_cast<uint2*>(&H[(size_t)f * (B_ * D_) + (size_t)b * D_ + d]) =
        *reinterpret_cast<const uint2*>(hb);

    if (f < F_ - 1) {
      int feat = feats[b * F_ + f];
      const float* row = tables + ((size_t)f * V_ + feat) * D_;
      float4 tv = *reinterpret_cast<const float4*>(&row[d]);
      s[0] += tv.x; s[1] += tv.y; s[2] += tv.z; s[3] += tv.w;
    }
  }
}

// ---------------------------------------------------------------------------
// Kernel 2: 256x256 8-phase GEMM, BK=64, 8 waves (2Mx4N), dbuf LDS.
// IDENTICAL schedule to R5 except the LDS is FOUR DISTINCT __shared__ objects
// (Ad0/Ad1/Bd0/Bd1) so the compiler's LDS-DMA alias tracking can prove each
// ds_read independent of in-flight global_load_lds DMAs into other buffers ->
// no per-phase conservative vmcnt drain. My VM4/VM0+barrier ledger provides
// the collective cross-wave certification (unchanged, audited).
// ---------------------------------------------------------------------------
#define STAGE(ARR, GB, HALF, KT)                                              \
  do {                                                                        \
    const ushort* _g = (GB) + (size_t)(HALF) * (128 * D_) + (size_t)(KT) * 64;\
    ushort* _l = &ARR[(HALF)*8192 + w * 512];                                 \
    gload_lds16(_g, _l);                                                      \
    gload_lds16(_g + 64 * D_, _l + 4096);                                     \
  } while (0)

#define LD_A(DST, LBASE, FIOFF)                                               \
  _Pragma("unroll") for (int _fj = 0; _fj < 4; ++_fj)                         \
  _Pragma("unroll") for (int _ks = 0; _ks < 2; ++_ks)                         \
      DST[_fj][_ks] = *reinterpret_cast<const bf16x8*>(                       \
          (LBASE) + ((((FIOFF) + _fj) * 2 + _ks) * 512));

#define LD_B(DST, LBASE, NFOFF)                                               \
  _Pragma("unroll") for (int _fn = 0; _fn < 2; ++_fn)                         \
  _Pragma("unroll") for (int _ks = 0; _ks < 2; ++_ks)                         \
      DST[_fn][_ks] = *reinterpret_cast<const bf16x8*>(                       \
          (LBASE) + ((((NFOFF) + _fn) * 2 + _ks) * 512));

#define Q_MFMA(AF, BF, R0, C0)                                                \
  do {                                                                        \
    __builtin_amdgcn_s_setprio(1);                                            \
    _Pragma("unroll") for (int _fj = 0; _fj < 4; ++_fj)                       \
    _Pragma("unroll") for (int _fn = 0; _fn < 2; ++_fn)                       \
    _Pragma("unroll") for (int _ks = 0; _ks < 2; ++_ks)                       \
        acc[(R0) + _fj][(C0) + _fn] =                                         \
            __builtin_amdgcn_mfma_f32_16x16x32_bf16(                          \
                AF[_fj][_ks], BF[_fn][_ks], acc[(R0) + _fj][(C0) + _fn],      \
                0, 0, 0);                                                     \
    __builtin_amdgcn_s_setprio(0);                                            \
  } while (0)

#define BAR __builtin_amdgcn_s_barrier()
#define SB0 __builtin_amdgcn_sched_barrier(0)
#define VM4 asm volatile("s_waitcnt vmcnt(4)")
#define VM0 asm volatile("s_waitcnt vmcnt(0)")
#define LG0 asm volatile("s_waitcnt lgkmcnt(0)")

__global__ __launch_bounds__(512, 2) void gemm_hw(
    const ushort* __restrict__ H,    // (F, B, D) bf16
    const ushort* __restrict__ Wt,   // (F, VP, D) bf16
    const float* __restrict__ bias,  // (F, V)
    float* __restrict__ out) {       // (B, F, V)
  __shared__ ushort Ad0[16384];  // 32 KB: A dbuf0 (2 half-tiles x 16KB)
  __shared__ ushort Ad1[16384];  // 32 KB: A dbuf1
  __shared__ ushort Bd0[16384];  // 32 KB: B dbuf0
  __shared__ ushort Bd1[16384];  // 32 KB: B dbuf1

  // bijective XCD swizzle: nwg=512, 512%8==0
  const int bid = blockIdx.x;
  const int swz = (bid & 7) * 64 + (bid >> 3);
  const int f = swz >> 6;
  const int r = swz & 63;
  const int mt = r >> 2, nt = r & 3;

  const int t = threadIdx.x;
  const int w = t >> 6, l = t & 63;
  const int wm = w >> 2;   // 0..1 (M)
  const int wn = w & 3;    // 0..3 (N)

  const ushort* Hf = H + (size_t)f * (B_ * D_);
  const ushort* Wf = Wt + (size_t)f * (VP * D_);

  // staging global source (pre-swizzled so linear LDS write = swizzled layout)
  const int srow = ((w >> 1) << 4) + (l >> 2);
  const int skx = ((w & 1) << 5) + ((((l & 3) << 3)) ^ (((l >> 5) & 1) << 4));
  const ushort* gA = Hf + (size_t)(mt * 256 + srow) * D_ + skx;
  const ushort* gB = Wf + (size_t)(nt * 256 + srow) * D_ + skx;

  // ds_read per-lane offset (ushorts): same swizzle on read side
  const int laneu =
      ((l & 15) << 5) + (((((l >> 4) << 4)) ^ (((l >> 3) & 1) << 5)) >> 1);
  const ushort* lA[2] = {&Ad0[wm * 8192 + laneu], &Ad1[wm * 8192 + laneu]};
  const ushort* lB[2] = {&Bd0[(wn >> 1) * 8192 + (wn & 1) * 4096 + laneu],
                         &Bd1[(wn >> 1) * 8192 + (wn & 1) * 4096 + laneu]};

  bf16x8 a0[4][2], a1[4][2], b0[2][2], b1[2][2];
  f32x4 acc[8][4] = {};

  // prologue: dbuf0{A0,A1,B0,B1}(T0) then dbuf1{A0,A1}(T1) -> 12 loads.
  // vmcnt(4) drains the 8 T0 loads, leaves the 4 dbuf1.A(T1) in flight.
  STAGE(Ad0, gA, 0, 0);
  STAGE(Ad0, gA, 1, 0);
  STAGE(Bd0, gB, 0, 0);
  STAGE(Bd0, gB, 1, 0);
  STAGE(Ad1, gA, 0, 1);
  STAGE(Ad1, gA, 1, 1);
  VM4;
  BAR;

#pragma unroll 1
  for (int i = 0; i < 8; ++i) {
    const int t1 = 2 * i + 1, t2 = 2 * i + 2, t3 = 2 * i + 3;
    const bool more = (i < 7);
    // PH1: reads a0,b0(T0); stage d1.B0(T1)
    LD_A(a0, lA[0], 0);
    LD_B(b0, lB[0], 0);
    STAGE(Bd1, gB, 0, t1);
    BAR;
    LG0;
    SB0;
    Q_MFMA(a0, b0, 0, 0);
    // PH2: reads a1(T0); stage d1.B1(T1)
    LD_A(a1, lA[0], 4);
    STAGE(Bd1, gB, 1, t1);
    BAR;
    LG0;
    SB0;
    Q_MFMA(a1, b0, 4, 0);
    // PH3: reads b1(T0); stage d0.A0(T2)  [d0.A last read PH2]
    LD_B(b1, lB[0], 2);
    if (more) STAGE(Ad0, gA, 0, t2);
    BAR;
    LG0;
    SB0;
    Q_MFMA(a0, b1, 0, 2);
    // PH4: stage d0.A1(T2); vmcnt(4) collective -> dbuf1(T1) landed
    if (more) {
      STAGE(Ad0, gA, 1, t2);
      VM4;
    } else {
      VM0;
    }
    BAR;
    SB0;
    Q_MFMA(a1, b1, 4, 2);
    // PH5: reads a0,b0(T1); stage d0.B0(T2)  [d0.B last read PH3]
    LD_A(a0, lA[1], 0);
    LD_B(b0, lB[1], 0);
    if (more) STAGE(Bd0, gB, 0, t2);
    BAR;
    LG0;
    SB0;
    Q_MFMA(a0, b0, 0, 0);
    // PH6: reads a1(T1); stage d0.B1(T2)
    LD_A(a1, lA[1], 4);
    if (more) STAGE(Bd0, gB, 1, t2);
    BAR;
    LG0;
    SB0;
    Q_MFMA(a1, b0, 4, 0);
    // PH7: reads b1(T1); stage d1.A0(T3)  [d1.A last read PH6]
    LD_B(b1, lB[1], 2);
    if (more) STAGE(Ad1, gA, 0, t3);
    BAR;
    LG0;
    SB0;
    Q_MFMA(a0, b1, 0, 2);
    // PH8: stage d1.A1(T3); vmcnt(4) collective -> dbuf0(T2) landed
    if (more) {
      STAGE(Ad1, gA, 1, t3);
      VM4;
    }
    BAR;
    SB0;
    Q_MFMA(a1, b1, 4, 2);
  }

  // epilogue: C layout col = lane&15, row = (lane>>4)*4 + q
  const float* bp = bias + f * V_;
  const int orow0 = mt * 256 + wm * 128 + ((l >> 4) << 2);
  const int ocol0 = nt * 256 + wn * 64 + (l & 15);
#pragma unroll
  for (int fi = 0; fi < 8; ++fi) {
#pragma unroll
    for (int fn = 0; fn < 4; ++fn) {
      int col = ocol0 + fn * 16;
      if (col < V_) {
        float bb = bp[col];
        int row = orow0 + fi * 16;
        float* op = out + (size_t)row * (F_ * V_) + (size_t)f * V_ + col;
#pragma unroll
        for (int q = 0; q < 4; ++q)
          op[(size_t)q * (F_ * V_)] = acc[fi][fn][q] + bb;
      }
    }
  }
}

// ---------------------------------------------------------------------------
extern "C" void kernel_launch(void* const* d_in, const int* in_sizes, int n_in,
                              void* d_out, int out_size, void* d_ws,
                              size_t ws_size, hipStream_t stream) {
  const float* emb = (const float*)d_in[0];     // (B, D)
  const int* feats = (const int*)d_in[1];       // (B, F)
  const float* tables = (const float*)d_in[2];  // (F, V, D)
  const float* gamma = (const float*)d_in[3];   // (D,)
  const float* beta = (const float*)d_in[4];    // (D,)
  const float* W = (const float*)d_in[5];       // (F, D, V)
  const float* bias = (const float*)d_in[6];    // (F, V)
  float* out = (float*)d_out;                   // (B, F, V)

  char* ws = (char*)d_ws;
  __hip_bfloat16* Hbuf = (__hip_bfloat16*)ws;  // F*B*D*2 = 64 MiB
  __hip_bfloat16* Wtbuf =
      (__hip_bfloat16*)(ws + (size_t)F_ * B_ * D_ * 2);  // F*VP*D*2 = 16 MiB

  transpose_w<<<dim3(D_ / 32, VP / 32, F_), dim3(32, 8), 0, stream>>>(W, Wtbuf);
  fuse_h<<<dim3(B_), dim3(256), 0, stream>>>(emb, feats, tables, gamma, beta,
                                             Hbuf);
  gemm_hw<<<dim3((B_ / 256) * (VP / 256) * F_), dim3(512), 0, stream>>>(
      (const ushort*)Hbuf, (const ushort*)Wtbuf, bias, out);
}